// Round 20
// baseline (460.025 us; speedup 1.0000x reference)
//
#include <hip/hip_runtime.h>
#include <math.h>

typedef _Float16 f16;
typedef _Float16 f16x2 __attribute__((ext_vector_type(2)));
typedef _Float16 f16x4 __attribute__((ext_vector_type(4)));
typedef _Float16 f16x8 __attribute__((ext_vector_type(8)));
typedef float f32x4 __attribute__((ext_vector_type(4)));

#define AS1 __attribute__((address_space(1)))
#define AS3 __attribute__((address_space(3)))

__device__ __forceinline__ void gload_lds16(const void* g, void* l) {
    __builtin_amdgcn_global_load_lds((AS1 void*)(g), (AS3 void*)(l), 16, 0, 0);
}

// fast transcendentals: v_exp_f32 (exp2) + v_rcp_f32, ~1 ulp, correct saturation
__device__ __forceinline__ float sigmoid_fast(float v) {
    return __builtin_amdgcn_rcpf(1.f + __builtin_amdgcn_exp2f(-1.44269504f * v));
}
__device__ __forceinline__ float tanh_fast(float v) {
    return 1.f - 2.f * __builtin_amdgcn_rcpf(1.f + __builtin_amdgcn_exp2f(2.88539008f * v));
}

// ---------------- fused LDS-tiled transpose+cast of W1|W3|W4|W5 -> WtQ[5120][256] ----------------
__global__ __launch_bounds__(256) void tposeq_kernel(
    const float* __restrict__ W1, const float* __restrict__ W3,
    const float* __restrict__ W4, const float* __restrict__ W5, f16* __restrict__ Wt) {
    __shared__ float T[64][65];
    const int y = blockIdx.y;
    const float* W; int nw, n0, orow;
    if (y < 32)      { W = W1; nw = 2048; n0 = y * 64;        orow = 0;    }
    else if (y < 48) { W = W3; nw = 1024; n0 = (y - 32) * 64; orow = 2048; }
    else if (y < 64) { W = W4; nw = 1024; n0 = (y - 48) * 64; orow = 3072; }
    else             { W = W5; nw = 1024; n0 = (y - 64) * 64; orow = 4096; }
    const int k0 = blockIdx.x * 64;
    const int tid = threadIdx.x;
    const int rr = tid >> 4, cc = (tid & 15) * 4;
#pragma unroll
    for (int p = 0; p < 4; ++p) {
        int k = rr + p * 16;
        float4 v = *(const float4*)&W[(size_t)(k0 + k) * nw + n0 + cc];
        T[k][cc] = v.x; T[k][cc + 1] = v.y; T[k][cc + 2] = v.z; T[k][cc + 3] = v.w;
    }
    __syncthreads();
#pragma unroll
    for (int p = 0; p < 4; ++p) {
        int n = rr + p * 16;
        f16x4 h;
        h[0] = (f16)T[cc][n]; h[1] = (f16)T[cc + 1][n];
        h[2] = (f16)T[cc + 2][n]; h[3] = (f16)T[cc + 3][n];
        *(f16x4*)&Wt[(size_t)(orow + n0 + n) * 256 + k0 + cc] = h;
    }
}

// ---------------- LDS-tiled transpose+cast: Wt[n][k] = (f16)W[k][n], 64x64 tiles (W2) ------------
__global__ __launch_bounds__(256) void tpose_kernel(const float* __restrict__ W, f16* __restrict__ Wt,
                                                    int K, int N) {
    __shared__ float T[64][65];
    const int k0 = blockIdx.x * 64, n0 = blockIdx.y * 64;
    const int tid = threadIdx.x;
    const int rr = tid >> 4, cc = (tid & 15) * 4;
#pragma unroll
    for (int p = 0; p < 4; ++p) {
        int k = rr + p * 16;
        float4 v = *(const float4*)&W[(size_t)(k0 + k) * N + n0 + cc];
        T[k][cc] = v.x; T[k][cc + 1] = v.y; T[k][cc + 2] = v.z; T[k][cc + 3] = v.w;
    }
    __syncthreads();
#pragma unroll
    for (int p = 0; p < 4; ++p) {
        int n = rr + p * 16;
        f16x4 h;
        h[0] = (f16)T[cc][n]; h[1] = (f16)T[cc + 1][n];
        h[2] = (f16)T[cc + 2][n]; h[3] = (f16)T[cc + 3][n];
        *(f16x4*)&Wt[(size_t)(n0 + n) * K + k0 + cc] = h;
    }
}

// ---------------- embedding cast to f16, padded rows zeroed ----------------
__global__ __launch_bounds__(256) void ecast_kernel(const float* __restrict__ emb, f16* __restrict__ E) {
    int r = blockIdx.x * 4 + (threadIdx.x >> 6);
    int c = (threadIdx.x & 63) * 4;
    float4 v = make_float4(0.f, 0.f, 0.f, 0.f);
    if (r < 10000) v = *(const float4*)&emb[(size_t)r * 256 + c];
    f16x4 h;
    h[0] = (f16)v.x; h[1] = (f16)v.y; h[2] = (f16)v.z; h[3] = (f16)v.w;
    *(f16x4*)&E[(size_t)r * 256 + c] = h;
}

// ---------------- GEMM: C = act(A @ Bt^T + bias), 160-row tiles, BK=32, double-buffered ----------
// r19: occupancy push. Epilogue VALU (transcendentals) ~ matmul cost at K=256 (r17: VALUBusy 36 >
// MfmaUtil 19); more co-resident blocks hide it. MODE0: two-pass 128-col epilogue shrinks Cs to
// 40 KB -> LDS 52 KB -> 3 blocks/CU. MODE1: BK=32 -> LDS 40 KB -> 3-4 blocks/CU.
// Row-phase swizzle (row>>1)&3 (r11-verified, 0 conflicts). 2-phase __syncthreads dbuf (r17-proven;
// counted-vmcnt / triple-buffer / 4-phase all measured null-to-negative).
// MODE 0 (N=5120): col<2048 relu+b1->O0[.,2048]; cols 2048..4095 W3/W4 interleaved (16-col
//   groups): even frag = sigmoid(.+b3), odd = tanh(.+b4) -> p=i*g -> O1 (Pt). col>=4096 relu->O3.
// MODE 1: tanh+bias -> O0 stride 1024
template <int MODE>
__global__ __launch_bounds__(512, 6) void gemm_main(
    const f16* __restrict__ A, const f16* __restrict__ Bt, int N, int K, int CT,
    const float* __restrict__ bb1, const float* __restrict__ bb3, const float* __restrict__ bb4,
    f16* __restrict__ O0, f16* __restrict__ O1, f16* __restrict__ O3) {
    constexpr int BN    = (MODE == 0) ? 256 : 128;
    constexpr int BK    = 32;
    constexpr int NF    = BN / 64;                 // per-wave 16-col fragments
    constexpr int WNOFF = BN / 4;                  // per-wave N span
    constexpr int SMASK = 3, RSH = 1;              // row-phase swizzle (BK=32)
    constexpr int ABUF  = 160 * BK;                // f16 per A buffer
    constexpr int BBUF  = BN * BK;
    constexpr int BUFSZ = ABUF + BBUF;
    constexpr int BIT   = BN / 128;                // B staging iters (512 thr, 16B each)
    constexpr int SMSZ  = (MODE == 0) ? 26624 : 20480;  // f16: 52 KB / 40 KB
    __shared__ __align__(16) f16 SM[SMSZ];
    f16* Cs = SM;                                  // 160x128 f16 overlay = 40 KB
    // bijective XCD remap (m204), then row-major decode: consecutive wg share A-panel
    const int nwg = gridDim.x, orig = blockIdx.x;
    const int q = nwg >> 3, rm = nwg & 7;
    const int xcd = orig & 7, loc = orig >> 3;
    const int wg = (xcd < rm ? xcd * (q + 1) : rm * (q + 1) + (xcd - rm) * q) + loc;
    const int rowT = wg / CT, colT = wg - rowT * CT;
    const int row0 = rowT * 160, col0 = colT * BN;

    const int tid = threadIdx.x;
    const int wave = tid >> 6, lane = tid & 63;
    const int wr = wave >> 2, wc = wave & 3;       // 2 x 4 wave grid
    const int lo16 = lane & 15, hi4 = lane >> 4;

    const bool PM = (MODE == 0) && (col0 >= 2048) && (col0 < 4096);  // block-uniform

    f32x4 acc[5][NF] = {};

    // ---- hoisted staging sources (k0-invariant) ----
    const f16* aptr[2]; int adst[2];
    const f16* bptr[BIT]; int bdst[BIT];
#pragma unroll
    for (int it = 0; it < 2; ++it) {
        int c = it * 512 + tid;                    // A: 640 chunks; it=1 valid for tid<128
        int r = c >> 2, sl = c & 3;
        int kc = (sl ^ ((r >> RSH) & SMASK)) << 3; // pre-swizzled global source (rule #21)
        aptr[it] = A + (size_t)(row0 + (r < 160 ? r : 0)) * K + kc;
        adst[it] = c * 8;
    }
#pragma unroll
    for (int it = 0; it < BIT; ++it) {
        int c = it * 512 + tid;                    // B: BN*4 chunks
        int r = c >> 2, sl = c & 3;
        int kc = (sl ^ ((r >> RSH) & SMASK)) << 3;
        int brow = col0 + r;
        if (PM) {                                   // W3/W4 16-col interleave remap (hoisted)
            int qc = col0 - 2048 + r;
            int grp = qc >> 5, q2 = qc & 31;
            brow = (q2 < 16) ? (2048 + grp * 16 + q2) : (3072 + grp * 16 + (q2 - 16));
        }
        bptr[it] = Bt + (size_t)brow * K + kc;
        bdst[it] = c * 8;
    }

    auto stage = [&](int buf, int k0) {
        f16* As = SM + buf * BUFSZ;
        f16* Bs = As + ABUF;
        gload_lds16(aptr[0] + k0, &As[adst[0]]);
        if (tid < 128) gload_lds16(aptr[1] + k0, &As[adst[1]]);
#pragma unroll
        for (int it = 0; it < BIT; ++it)
            gload_lds16(bptr[it] + k0, &Bs[bdst[it]]);
    };

    const int nt = K >> 5;
    stage(0, 0);
    __syncthreads();                               // buf0 ready
    for (int t = 0; t < nt; ++t) {
        if (t + 1 < nt) stage((t + 1) & 1, (t + 1) << 5);   // prefetch in flight during MFMA
        const f16* As = SM + (t & 1) * BUFSZ;
        const f16* Bs = As + ABUF;
        f16x8 af[5], bf[NF];
#pragma unroll
        for (int m = 0; m < 5; ++m) {
            int row = wr * 80 + m * 16 + lo16;
            af[m] = *(const f16x8*)&As[row * BK + ((hi4 ^ ((row >> RSH) & SMASK)) << 3)];
        }
#pragma unroll
        for (int n = 0; n < NF; ++n) {
            int row = wc * WNOFF + n * 16 + lo16;
            bf[n] = *(const f16x8*)&Bs[row * BK + ((hi4 ^ ((row >> RSH) & SMASK)) << 3)];
        }
#pragma unroll
        for (int m = 0; m < 5; ++m)
#pragma unroll
            for (int n = 0; n < NF; ++n)
                acc[m][n] = __builtin_amdgcn_mfma_f32_16x16x32_f16(af[m], bf[n], acc[m][n], 0, 0, 0);
        __syncthreads();   // drains prefetch (covered by MFMA + co-resident blocks) + seals reads
    }

    if (MODE == 1) {
        // tanh+bias epilogue -> 160x128 tile of O0 (stride 1024)
        const float* bp = bb1 + col0;
#pragma unroll
        for (int n = 0; n < 2; ++n) {
            int col = wc * 32 + n * 16 + lo16;     // [0,128)
            float b = bp[col];
            int ch = col >> 3, el = col & 7;
#pragma unroll
            for (int m = 0; m < 5; ++m)
#pragma unroll
                for (int j = 0; j < 4; ++j) {
                    int row = wr * 80 + m * 16 + hi4 * 4 + j;
                    Cs[row * 128 + ((ch ^ (row & 15)) << 3) + el] = (f16)tanh_fast(acc[m][n][j] + b);
                }
        }
        __syncthreads();
#pragma unroll
        for (int it = 0; it < 5; ++it) {           // 160x16 chunks = 2560 = 5x512
            int idx = it * 512 + tid;
            int row = idx >> 4, ch = idx & 15;
            f16x8 v = *(const f16x8*)&Cs[row * 128 + ((ch ^ (row & 15)) << 3)];
            *(f16x8*)&O0[(size_t)(row0 + row) * 1024 + col0 + ch * 8] = v;
        }
        return;
    }

    if (PM) {
        // p-fusion epilogue: p = sigmoid(acc_even + b3) * tanh(acc_odd + b4) -> 160x128 Pt tile
        const int pcol0 = (col0 - 2048) >> 1;
#pragma unroll
        for (int p = 0; p < 2; ++p) {
            int colP = wc * 32 + p * 16 + lo16;    // [0,128) local Pt col
            float bi = bb3[pcol0 + colP], bg = bb4[pcol0 + colP];
            int ch = colP >> 3, el = colP & 7;
#pragma unroll
            for (int m = 0; m < 5; ++m)
#pragma unroll
                for (int j = 0; j < 4; ++j) {
                    int row = wr * 80 + m * 16 + hi4 * 4 + j;
                    float pi = sigmoid_fast(acc[m][2 * p][j] + bi);
                    float pg = tanh_fast(acc[m][2 * p + 1][j] + bg);
                    Cs[row * 128 + ((ch ^ (row & 15)) << 3) + el] = (f16)(pi * pg);
                }
        }
        __syncthreads();
#pragma unroll
        for (int it = 0; it < 5; ++it) {           // 160x16 chunks = 2560 = 5x512
            int idx = it * 512 + tid;
            int row = idx >> 4, ch = idx & 15;
            f16x8 v = *(const f16x8*)&Cs[row * 128 + ((ch ^ (row & 15)) << 3)];
            *(f16x8*)&O1[(size_t)(row0 + row) * 1024 + pcol0 + ch * 8] = v;
        }
        return;
    }

    // MODE 0 non-interleaved tiles: relu (+b1 for col<2048); TWO 128-col passes through a 40 KB Cs
    f16* Oe; size_t ostr; const float* bp;
    if (col0 < 2048) { Oe = O0 + col0;          ostr = 2048; bp = bb1 + col0; }
    else             { Oe = O3 + (col0 - 4096); ostr = 1024; bp = nullptr;    }

#pragma unroll
    for (int pass = 0; pass < 2; ++pass) {
        if ((wc >> 1) == pass) {                   // waves owning cols [pass*128, pass*128+128)
#pragma unroll
            for (int n = 0; n < 4; ++n) {
                int colL = (wc & 1) * 64 + n * 16 + lo16;   // [0,128) local
                float b = bp ? bp[pass * 128 + colL] : 0.f;
                int ch = colL >> 3, el = colL & 7;
#pragma unroll
                for (int m = 0; m < 5; ++m)
#pragma unroll
                    for (int j = 0; j < 4; ++j) {
                        int row = wr * 80 + m * 16 + hi4 * 4 + j;
                        Cs[row * 128 + ((ch ^ (row & 15)) << 3) + el] =
                            (f16)fmaxf(acc[m][n][j] + b, 0.f);
                    }
            }
        }
        __syncthreads();
#pragma unroll
        for (int it = 0; it < 5; ++it) {           // 160x16 chunks = 2560 = 5x512
            int idx = it * 512 + tid;
            int row = idx >> 4, ch = idx & 15;
            f16x8 v = *(const f16x8*)&Cs[row * 128 + ((ch ^ (row & 15)) << 3)];
            *(f16x8*)&Oe[(size_t)(row0 + row) * ostr + pass * 128 + ch * 8] = v;
        }
        if (pass == 0) __syncthreads();            // seal Cs before pass-1 writes
    }
}

// ---------------- scan over T, XCD-sliced: block = (batch b, unit-slice x of 128) ----------------
// blockIdx = b*8 + x -> round-robin dispatch pins slice x to XCD x (L2 affinity).
// 32-slot / 20-deep static software pipeline: 60 loads in flight (vmcnt cap 63).
__global__ __launch_bounds__(64) void scan_slice_kernel(
    const int* __restrict__ tokens, const f16* __restrict__ Mt, const f16* __restrict__ Pt,
    const f16* __restrict__ Ut, const float* __restrict__ state0,
    const float* __restrict__ Wout, float* __restrict__ partial) {
    __shared__ int toks[288];
    const int bid = blockIdx.x;
    const int b = bid >> 3, x = bid & 7;
    const int lane = threadIdx.x;
    for (int t = lane; t < 288; t += 64) toks[t] = (t < 250) ? tokens[b * 250 + t] : 0;
    __syncthreads();

    const int u0 = x * 128 + lane * 2;
    float2 sv = *(const float2*)&state0[(size_t)b * 1024 + u0];
    float s0 = sv.x, s1 = sv.y;

    f16x2 m[32], p[32], u[32];
#pragma unroll
    for (int k = 0; k < 20; ++k) {   // preload t=0..19 into slots 0..19
        size_t nb = (size_t)toks[k] * 1024 + u0;
        m[k] = *(const f16x2*)&Mt[nb];
        p[k] = *(const f16x2*)&Pt[nb];
        u[k] = *(const f16x2*)&Ut[nb];
    }

    // main: t = 0..223 (7 x 32 unrolled, slots static); loads target t+20
    for (int tb = 0; tb < 224; tb += 32) {
#pragma unroll
        for (int k = 0; k < 32; ++k) {
            const int ls = (k + 20) & 31;        // compile-time slot for t+20
            size_t nb = (size_t)toks[tb + k + 20] * 1024 + u0;
            m[ls] = *(const f16x2*)&Mt[nb];
            p[ls] = *(const f16x2*)&Pt[nb];
            u[ls] = *(const f16x2*)&Ut[nb];
            float y0 = fmaxf((float)m[k][0] * s0 + (float)p[k][0], 0.f);
            s0 = fmaxf((float)u[k][0] + y0, 0.f);
            float y1 = fmaxf((float)m[k][1] * s1 + (float)p[k][1], 0.f);
            s1 = fmaxf((float)u[k][1] + y1, 0.f);
        }
    }
    // tail: t = 224..249 use slots 0..25; slots 20..25 reloaded with t=244..249
#pragma unroll
    for (int k = 0; k < 26; ++k) {
        if (k < 6) {
            const int ls = k + 20;
            size_t nb = (size_t)toks[244 + k] * 1024 + u0;
            m[ls] = *(const f16x2*)&Mt[nb];
            p[ls] = *(const f16x2*)&Pt[nb];
            u[ls] = *(const f16x2*)&Ut[nb];
        }
        float y0 = fmaxf((float)m[k][0] * s0 + (float)p[k][0], 0.f);
        s0 = fmaxf((float)u[k][0] + y0, 0.f);
        float y1 = fmaxf((float)m[k][1] * s1 + (float)p[k][1], 0.f);
        s1 = fmaxf((float)u[k][1] + y1, 0.f);
    }

    float2 wv = *(const float2*)&Wout[u0];
    float part = s0 * wv.x + s1 * wv.y;
#pragma unroll
    for (int o = 32; o > 0; o >>= 1) part += __shfl_down(part, o, 64);
    if (lane == 0) partial[bid] = part;
}

// ---------------- final reduce: out[b] = sigmoid(sum_x partial[b*8+x] + bout) ----------------
__global__ __launch_bounds__(256) void final_kernel(const float* __restrict__ partial,
                                                    const float* __restrict__ bout,
                                                    float* __restrict__ out) {
    int b = threadIdx.x;
    float tot = bout[0];
#pragma unroll
    for (int w = 0; w < 8; ++w) tot += partial[b * 8 + w];
    out[b] = sigmoid_fast(tot);
}

extern "C" void kernel_launch(void* const* d_in, const int* in_sizes, int n_in,
                              void* d_out, int out_size, void* d_ws, size_t ws_size,
                              hipStream_t stream) {
    const int*   tokens = (const int*)  d_in[0];
    const float* emb    = (const float*)d_in[1];
    const float* W1     = (const float*)d_in[2];
    const float* b1     = (const float*)d_in[3];
    const float* W2     = (const float*)d_in[4];
    const float* b2     = (const float*)d_in[5];
    const float* W3     = (const float*)d_in[6];
    const float* b3     = (const float*)d_in[7];
    const float* W4     = (const float*)d_in[8];
    const float* b4     = (const float*)d_in[9];
    const float* W5     = (const float*)d_in[10];
    const float* Wout   = (const float*)d_in[11];
    const float* bout   = (const float*)d_in[12];
    const float* state0 = (const float*)d_in[13];
    float* out = (float*)d_out;

    const int RP = 10240;  // padded vocab rows: 64 x 160 (gemm M-tiles)

    char* ws = (char*)d_ws;
    size_t off = 0;
    auto alloc = [&](size_t bytes) -> void* {
        void* p = ws + off;
        off += (bytes + 255) & ~(size_t)255;
        return p;
    };
    f16* WtQ = (f16*)alloc((size_t)5120 * 256 * 2);   // W1|W3|W4|W5 transposed [5120][256]
    f16* Wt2 = (f16*)alloc((size_t)1024 * 2048 * 2);
    f16* E   = (f16*)alloc((size_t)RP * 256 * 2);
    f16* Rb  = (f16*)alloc((size_t)RP * 2048 * 2);
    f16* Mt  = (f16*)alloc((size_t)RP * 1024 * 2);
    f16* Pt  = (f16*)alloc((size_t)RP * 1024 * 2);
    f16* Ut  = (f16*)alloc((size_t)RP * 1024 * 2);
    float* partial = (float*)alloc((size_t)2048 * 4);
    (void)ws_size; (void)in_sizes; (void)n_in; (void)out_size;

    // weights -> f16 transposed [N][K] (LDS-tiled, coalesced both ways)
    tposeq_kernel<<<dim3(4, 80), 256, 0, stream>>>(W1, W3, W4, W5, WtQ);
    tpose_kernel<<<dim3(32, 16), 256, 0, stream>>>(W2, Wt2, 2048, 1024);
    ecast_kernel<<<RP / 4, 256, 0, stream>>>(emb, E);

    // fused per-vocab tables: E @ [W1 | W3/W4 interleaved | W5]  (N=5120, K=256)
    // 160x256 tile, BK=32: grid 64x20 = 1280, 3 blocks/CU co-resident
    gemm_main<0><<<(RP / 160) * (5120 / 256), 512, 0, stream>>>(
        E, WtQ, 5120, 256, 5120 / 256, b1, b3, b4, Rb, Pt, Ut);
    // Mt = tanh(relu(...) @ W2 + b2)  (N=1024, K=2048)
    // 160x128 tile, BK=32: grid 64x8 = 512, 3-4 blocks/CU co-resident
    gemm_main<1><<<(RP / 160) * (1024 / 128), 512, 0, stream>>>(
        Rb, Wt2, 1024, 2048, 1024 / 128, b2, nullptr, nullptr, Mt, nullptr, nullptr);

    // scan (XCD-sliced, 20-deep pipelined) + final projection reduce
    scan_slice_kernel<<<2048, 64, 0, stream>>>(tokens, Mt, Pt, Ut, state0, Wout, partial);
    final_kernel<<<1, 256, 0, stream>>>(partial, bout, out);
}

// Round 21
// 149.632 us; speedup vs baseline: 3.0744x; 3.0744x over previous
//
#include <hip/hip_runtime.h>
#include <math.h>

typedef _Float16 f16;
typedef _Float16 f16x2 __attribute__((ext_vector_type(2)));
typedef _Float16 f16x4 __attribute__((ext_vector_type(4)));
typedef _Float16 f16x8 __attribute__((ext_vector_type(8)));
typedef float f32x4 __attribute__((ext_vector_type(4)));

#define AS1 __attribute__((address_space(1)))
#define AS3 __attribute__((address_space(3)))

__device__ __forceinline__ void gload_lds16(const void* g, void* l) {
    __builtin_amdgcn_global_load_lds((AS1 void*)(g), (AS3 void*)(l), 16, 0, 0);
}

// fast transcendentals: v_exp_f32 (exp2) + v_rcp_f32, ~1 ulp, correct saturation
__device__ __forceinline__ float sigmoid_fast(float v) {
    return __builtin_amdgcn_rcpf(1.f + __builtin_amdgcn_exp2f(-1.44269504f * v));
}
__device__ __forceinline__ float tanh_fast(float v) {
    return 1.f - 2.f * __builtin_amdgcn_rcpf(1.f + __builtin_amdgcn_exp2f(2.88539008f * v));
}

// ---------------- fused LDS-tiled transpose+cast of W1|W3|W4|W5 -> WtQ[5120][256] ----------------
__global__ __launch_bounds__(256) void tposeq_kernel(
    const float* __restrict__ W1, const float* __restrict__ W3,
    const float* __restrict__ W4, const float* __restrict__ W5, f16* __restrict__ Wt) {
    __shared__ float T[64][65];
    const int y = blockIdx.y;
    const float* W; int nw, n0, orow;
    if (y < 32)      { W = W1; nw = 2048; n0 = y * 64;        orow = 0;    }
    else if (y < 48) { W = W3; nw = 1024; n0 = (y - 32) * 64; orow = 2048; }
    else if (y < 64) { W = W4; nw = 1024; n0 = (y - 48) * 64; orow = 3072; }
    else             { W = W5; nw = 1024; n0 = (y - 64) * 64; orow = 4096; }
    const int k0 = blockIdx.x * 64;
    const int tid = threadIdx.x;
    const int rr = tid >> 4, cc = (tid & 15) * 4;
#pragma unroll
    for (int p = 0; p < 4; ++p) {
        int k = rr + p * 16;
        float4 v = *(const float4*)&W[(size_t)(k0 + k) * nw + n0 + cc];
        T[k][cc] = v.x; T[k][cc + 1] = v.y; T[k][cc + 2] = v.z; T[k][cc + 3] = v.w;
    }
    __syncthreads();
#pragma unroll
    for (int p = 0; p < 4; ++p) {
        int n = rr + p * 16;
        f16x4 h;
        h[0] = (f16)T[cc][n]; h[1] = (f16)T[cc + 1][n];
        h[2] = (f16)T[cc + 2][n]; h[3] = (f16)T[cc + 3][n];
        *(f16x4*)&Wt[(size_t)(orow + n0 + n) * 256 + k0 + cc] = h;
    }
}

// ---------------- LDS-tiled transpose+cast: Wt[n][k] = (f16)W[k][n], 64x64 tiles (W2) ------------
__global__ __launch_bounds__(256) void tpose_kernel(const float* __restrict__ W, f16* __restrict__ Wt,
                                                    int K, int N) {
    __shared__ float T[64][65];
    const int k0 = blockIdx.x * 64, n0 = blockIdx.y * 64;
    const int tid = threadIdx.x;
    const int rr = tid >> 4, cc = (tid & 15) * 4;
#pragma unroll
    for (int p = 0; p < 4; ++p) {
        int k = rr + p * 16;
        float4 v = *(const float4*)&W[(size_t)(k0 + k) * N + n0 + cc];
        T[k][cc] = v.x; T[k][cc + 1] = v.y; T[k][cc + 2] = v.z; T[k][cc + 3] = v.w;
    }
    __syncthreads();
#pragma unroll
    for (int p = 0; p < 4; ++p) {
        int n = rr + p * 16;
        f16x4 h;
        h[0] = (f16)T[cc][n]; h[1] = (f16)T[cc + 1][n];
        h[2] = (f16)T[cc + 2][n]; h[3] = (f16)T[cc + 3][n];
        *(f16x4*)&Wt[(size_t)(n0 + n) * K + k0 + cc] = h;
    }
}

// ---------------- embedding cast to f16, padded rows zeroed ----------------
__global__ __launch_bounds__(256) void ecast_kernel(const float* __restrict__ emb, f16* __restrict__ E) {
    int r = blockIdx.x * 4 + (threadIdx.x >> 6);
    int c = (threadIdx.x & 63) * 4;
    float4 v = make_float4(0.f, 0.f, 0.f, 0.f);
    if (r < 10000) v = *(const float4*)&emb[(size_t)r * 256 + c];
    f16x4 h;
    h[0] = (f16)v.x; h[1] = (f16)v.y; h[2] = (f16)v.z; h[3] = (f16)v.w;
    *(f16x4*)&E[(size_t)r * 256 + c] = h;
}

// ---------------- GEMM: C = act(A @ Bt^T + bias), 160-row tiles, double-buffered ----------------
// r21 = r17 restore (155.6 us measured): LDS < 80 KB -> 2 blocks/CU (16 waves/CU). VGPR cap at
// launch_bounds(512,4) = 128 — fits acc+frags (r20's (512,6) capped at 85 -> spill catastrophe).
//   MODE 0: 160x256, BK=32 (dbuf 2x26 KB; alloc = Cs 80 KB = exactly 2/CU). Row-phase swizzle
//           (row>>1)&3 (r11-verified, 0 conflicts). grid 64x20 = 1280.
//   MODE 1: 160x128, BK=64 (dbuf 72 KB -> 2/CU). grid 64x8 = 512.
// 8 waves (2M x 4N); per-wave 80x(BN/4): acc[5][4] / acc[5][2].
// MODE 0 (N=5120): col<2048 relu+b1->O0[.,2048]; cols 2048..4095 W3/W4 interleaved (16-col
//   groups): even frag = sigmoid(.+b3), odd = tanh(.+b4) -> p=i*g -> O1 (Pt). col>=4096 relu->O3.
// MODE 1: tanh+bias -> O0 stride 1024
template <int MODE>
__global__ __launch_bounds__(512, 4) void gemm_main(
    const f16* __restrict__ A, const f16* __restrict__ Bt, int N, int K, int CT,
    const float* __restrict__ bb1, const float* __restrict__ bb3, const float* __restrict__ bb4,
    f16* __restrict__ O0, f16* __restrict__ O1, f16* __restrict__ O3) {
    constexpr int BN    = (MODE == 0) ? 256 : 128;
    constexpr int BK    = (MODE == 0) ? 32 : 64;
    constexpr int NF    = BN / 64;                 // per-wave 16-col fragments
    constexpr int WNOFF = BN / 4;                  // per-wave N span
    constexpr int SLOTS = BK / 8, SMASK = SLOTS - 1;
    constexpr int LOG2S = (BK == 32) ? 2 : 3;
    constexpr int RSH   = (BK == 32) ? 1 : 0;      // row-phase shift for swizzle
    constexpr int ABUF  = 160 * BK;                // f16 per A buffer
    constexpr int BBUF  = BN * BK;
    constexpr int BUFSZ = ABUF + BBUF;
    constexpr int ACH   = 160 * SLOTS;             // A 16B chunks
    constexpr int BCH   = BN * SLOTS;              // B 16B chunks (1024 both modes)
    constexpr int AIT   = (ACH + 511) / 512;
    constexpr int BIT   = BCH / 512;
    constexpr int SMSZ  = (MODE == 0) ? 40960 : 36864;   // f16: 80 KB / 72 KB
    __shared__ __align__(16) f16 SM[SMSZ];
    f16* Cs = SM;
    // bijective XCD remap (m204), then row-major decode: consecutive wg share A-panel
    const int nwg = gridDim.x, orig = blockIdx.x;
    const int q = nwg >> 3, rm = nwg & 7;
    const int xcd = orig & 7, loc = orig >> 3;
    const int wg = (xcd < rm ? xcd * (q + 1) : rm * (q + 1) + (xcd - rm) * q) + loc;
    const int rowT = wg / CT, colT = wg - rowT * CT;
    const int row0 = rowT * 160, col0 = colT * BN;

    const int tid = threadIdx.x;
    const int wave = tid >> 6, lane = tid & 63;
    const int wr = wave >> 2, wc = wave & 3;       // 2 x 4 wave grid
    const int lo16 = lane & 15, hi4 = lane >> 4;

    const bool PM = (MODE == 0) && (col0 >= 2048) && (col0 < 4096);  // block-uniform

    f32x4 acc[5][NF] = {};

    // ---- hoisted staging sources (k0-invariant) ----
    const f16* aptr[AIT]; int adst[AIT];
    const f16* bptr[BIT]; int bdst[BIT];
#pragma unroll
    for (int it = 0; it < AIT; ++it) {
        int c = it * 512 + tid;
        int r = c >> LOG2S, sl = c & SMASK;
        int kc = (sl ^ ((r >> RSH) & SMASK)) << 3;  // pre-swizzled global source (rule #21)
        aptr[it] = A + (size_t)(row0 + (r < 160 ? r : 0)) * K + kc;
        adst[it] = c * 8;
    }
#pragma unroll
    for (int it = 0; it < BIT; ++it) {
        int c = it * 512 + tid;
        int r = c >> LOG2S, sl = c & SMASK;
        int kc = (sl ^ ((r >> RSH) & SMASK)) << 3;
        int brow = col0 + r;
        if (PM) {                                   // W3/W4 16-col interleave remap (hoisted)
            int qc = col0 - 2048 + r;
            int grp = qc >> 5, q2 = qc & 31;
            brow = (q2 < 16) ? (2048 + grp * 16 + q2) : (3072 + grp * 16 + (q2 - 16));
        }
        bptr[it] = Bt + (size_t)brow * K + kc;
        bdst[it] = c * 8;
    }

    auto stage = [&](int buf, int k0) {
        f16* As = SM + buf * BUFSZ;
        f16* Bs = As + ABUF;
#pragma unroll
        for (int it = 0; it < AIT; ++it)
            if ((it + 1) * 512 <= ACH || tid < ACH - it * 512)
                gload_lds16(aptr[it] + k0, &As[adst[it]]);
#pragma unroll
        for (int it = 0; it < BIT; ++it)
            gload_lds16(bptr[it] + k0, &Bs[bdst[it]]);
    };

    const int nt = K / BK;
    stage(0, 0);
    __syncthreads();                               // buf0 ready
    for (int t = 0; t < nt; ++t) {
        if (t + 1 < nt) stage((t + 1) & 1, (t + 1) * BK);   // prefetch in flight during MFMA
        const f16* As = SM + (t & 1) * BUFSZ;
        const f16* Bs = As + ABUF;
#pragma unroll
        for (int kk = 0; kk < BK; kk += 32) {
            const int s0 = (kk >> 3) + hi4;
            f16x8 af[5], bf[NF];
#pragma unroll
            for (int m = 0; m < 5; ++m) {
                int row = wr * 80 + m * 16 + lo16;
                af[m] = *(const f16x8*)&As[row * BK + ((s0 ^ ((row >> RSH) & SMASK)) << 3)];
            }
#pragma unroll
            for (int n = 0; n < NF; ++n) {
                int row = wc * WNOFF + n * 16 + lo16;
                bf[n] = *(const f16x8*)&Bs[row * BK + ((s0 ^ ((row >> RSH) & SMASK)) << 3)];
            }
#pragma unroll
            for (int m = 0; m < 5; ++m)
#pragma unroll
                for (int n = 0; n < NF; ++n)
                    acc[m][n] = __builtin_amdgcn_mfma_f32_16x16x32_f16(af[m], bf[n], acc[m][n], 0, 0, 0);
        }
        __syncthreads();   // drains prefetch (covered by MFMA + co-resident block) + seals reads
    }

    if (MODE == 1) {
        // tanh+bias epilogue -> 160x128 tile of O0 (stride 1024)
        const float* bp = bb1 + col0;
#pragma unroll
        for (int n = 0; n < 2; ++n) {
            int col = wc * 32 + n * 16 + lo16;     // [0,128)
            float b = bp[col];
            int ch = col >> 3, el = col & 7;
#pragma unroll
            for (int m = 0; m < 5; ++m)
#pragma unroll
                for (int j = 0; j < 4; ++j) {
                    int row = wr * 80 + m * 16 + hi4 * 4 + j;
                    Cs[row * 128 + ((ch ^ (row & 15)) << 3) + el] = (f16)tanh_fast(acc[m][n][j] + b);
                }
        }
        __syncthreads();
#pragma unroll
        for (int it = 0; it < 5; ++it) {           // 160x16 chunks = 2560 = 5x512
            int idx = it * 512 + tid;
            int row = idx >> 4, ch = idx & 15;
            f16x8 v = *(const f16x8*)&Cs[row * 128 + ((ch ^ (row & 15)) << 3)];
            *(f16x8*)&O0[(size_t)(row0 + row) * 1024 + col0 + ch * 8] = v;
        }
        return;
    }

    if (PM) {
        // p-fusion epilogue: p = sigmoid(acc_even + b3) * tanh(acc_odd + b4) -> 160x128 Pt tile
        const int pcol0 = (col0 - 2048) >> 1;
#pragma unroll
        for (int p = 0; p < 2; ++p) {
            int colP = wc * 32 + p * 16 + lo16;    // [0,128) local Pt col
            float bi = bb3[pcol0 + colP], bg = bb4[pcol0 + colP];
            int ch = colP >> 3, el = colP & 7;
#pragma unroll
            for (int m = 0; m < 5; ++m)
#pragma unroll
                for (int j = 0; j < 4; ++j) {
                    int row = wr * 80 + m * 16 + hi4 * 4 + j;
                    float pi = sigmoid_fast(acc[m][2 * p][j] + bi);
                    float pg = tanh_fast(acc[m][2 * p + 1][j] + bg);
                    Cs[row * 128 + ((ch ^ (row & 15)) << 3) + el] = (f16)(pi * pg);
                }
        }
        __syncthreads();
#pragma unroll
        for (int it = 0; it < 5; ++it) {           // 160x16 chunks = 2560 = 5x512
            int idx = it * 512 + tid;
            int row = idx >> 4, ch = idx & 15;
            f16x8 v = *(const f16x8*)&Cs[row * 128 + ((ch ^ (row & 15)) << 3)];
            *(f16x8*)&O1[(size_t)(row0 + row) * 1024 + pcol0 + ch * 8] = v;
        }
        return;
    }

    // MODE 0 non-interleaved tiles: relu (+b1 for col<2048)
    f16* Oe; size_t ostr; const float* bp;
    if (col0 < 2048) { Oe = O0 + col0;          ostr = 2048; bp = bb1 + col0; }
    else             { Oe = O3 + (col0 - 4096); ostr = 1024; bp = nullptr;    }

#pragma unroll
    for (int n = 0; n < NF; ++n) {
        int col = wc * WNOFF + n * 16 + lo16;      // [0,256)
        float b = bp ? bp[col] : 0.f;
        int ch = col >> 3, el = col & 7;
#pragma unroll
        for (int m = 0; m < 5; ++m)
#pragma unroll
            for (int j = 0; j < 4; ++j) {
                int row = wr * 80 + m * 16 + hi4 * 4 + j;
                Cs[row * 256 + ((ch ^ (row & 31)) << 3) + el] = (f16)fmaxf(acc[m][n][j] + b, 0.f);
            }
    }
    __syncthreads();

    // coalesced store: 160x32 chunks = 5120 = 10x512; 32 lanes cover one 512B row
#pragma unroll
    for (int it = 0; it < 10; ++it) {
        int idx = it * 512 + tid;
        int row = idx >> 5, ch = idx & 31;
        f16x8 v = *(const f16x8*)&Cs[row * 256 + ((ch ^ (row & 31)) << 3)];
        *(f16x8*)&Oe[(size_t)(row0 + row) * ostr + ch * 8] = v;
    }
}

// ---------------- scan over T, XCD-sliced: block = (batch b, unit-slice x of 128) ----------------
// blockIdx = b*8 + x -> round-robin dispatch pins slice x to XCD x (L2 affinity).
// 32-slot / 20-deep static software pipeline: 60 loads in flight (vmcnt cap 63).
__global__ __launch_bounds__(64) void scan_slice_kernel(
    const int* __restrict__ tokens, const f16* __restrict__ Mt, const f16* __restrict__ Pt,
    const f16* __restrict__ Ut, const float* __restrict__ state0,
    const float* __restrict__ Wout, float* __restrict__ partial) {
    __shared__ int toks[288];
    const int bid = blockIdx.x;
    const int b = bid >> 3, x = bid & 7;
    const int lane = threadIdx.x;
    for (int t = lane; t < 288; t += 64) toks[t] = (t < 250) ? tokens[b * 250 + t] : 0;
    __syncthreads();

    const int u0 = x * 128 + lane * 2;
    float2 sv = *(const float2*)&state0[(size_t)b * 1024 + u0];
    float s0 = sv.x, s1 = sv.y;

    f16x2 m[32], p[32], u[32];
#pragma unroll
    for (int k = 0; k < 20; ++k) {   // preload t=0..19 into slots 0..19
        size_t nb = (size_t)toks[k] * 1024 + u0;
        m[k] = *(const f16x2*)&Mt[nb];
        p[k] = *(const f16x2*)&Pt[nb];
        u[k] = *(const f16x2*)&Ut[nb];
    }

    // main: t = 0..223 (7 x 32 unrolled, slots static); loads target t+20
    for (int tb = 0; tb < 224; tb += 32) {
#pragma unroll
        for (int k = 0; k < 32; ++k) {
            const int ls = (k + 20) & 31;        // compile-time slot for t+20
            size_t nb = (size_t)toks[tb + k + 20] * 1024 + u0;
            m[ls] = *(const f16x2*)&Mt[nb];
            p[ls] = *(const f16x2*)&Pt[nb];
            u[ls] = *(const f16x2*)&Ut[nb];
            float y0 = fmaxf((float)m[k][0] * s0 + (float)p[k][0], 0.f);
            s0 = fmaxf((float)u[k][0] + y0, 0.f);
            float y1 = fmaxf((float)m[k][1] * s1 + (float)p[k][1], 0.f);
            s1 = fmaxf((float)u[k][1] + y1, 0.f);
        }
    }
    // tail: t = 224..249 use slots 0..25; slots 20..25 reloaded with t=244..249
#pragma unroll
    for (int k = 0; k < 26; ++k) {
        if (k < 6) {
            const int ls = k + 20;
            size_t nb = (size_t)toks[244 + k] * 1024 + u0;
            m[ls] = *(const f16x2*)&Mt[nb];
            p[ls] = *(const f16x2*)&Pt[nb];
            u[ls] = *(const f16x2*)&Ut[nb];
        }
        float y0 = fmaxf((float)m[k][0] * s0 + (float)p[k][0], 0.f);
        s0 = fmaxf((float)u[k][0] + y0, 0.f);
        float y1 = fmaxf((float)m[k][1] * s1 + (float)p[k][1], 0.f);
        s1 = fmaxf((float)u[k][1] + y1, 0.f);
    }

    float2 wv = *(const float2*)&Wout[u0];
    float part = s0 * wv.x + s1 * wv.y;
#pragma unroll
    for (int o = 32; o > 0; o >>= 1) part += __shfl_down(part, o, 64);
    if (lane == 0) partial[bid] = part;
}

// ---------------- final reduce: out[b] = sigmoid(sum_x partial[b*8+x] + bout) ----------------
__global__ __launch_bounds__(256) void final_kernel(const float* __restrict__ partial,
                                                    const float* __restrict__ bout,
                                                    float* __restrict__ out) {
    int b = threadIdx.x;
    float tot = bout[0];
#pragma unroll
    for (int w = 0; w < 8; ++w) tot += partial[b * 8 + w];
    out[b] = sigmoid_fast(tot);
}

extern "C" void kernel_launch(void* const* d_in, const int* in_sizes, int n_in,
                              void* d_out, int out_size, void* d_ws, size_t ws_size,
                              hipStream_t stream) {
    const int*   tokens = (const int*)  d_in[0];
    const float* emb    = (const float*)d_in[1];
    const float* W1     = (const float*)d_in[2];
    const float* b1     = (const float*)d_in[3];
    const float* W2     = (const float*)d_in[4];
    const float* b2     = (const float*)d_in[5];
    const float* W3     = (const float*)d_in[6];
    const float* b3     = (const float*)d_in[7];
    const float* W4     = (const float*)d_in[8];
    const float* b4     = (const float*)d_in[9];
    const float* W5     = (const float*)d_in[10];
    const float* Wout   = (const float*)d_in[11];
    const float* bout   = (const float*)d_in[12];
    const float* state0 = (const float*)d_in[13];
    float* out = (float*)d_out;

    const int RP = 10240;  // padded vocab rows: 64 x 160 (gemm M-tiles)

    char* ws = (char*)d_ws;
    size_t off = 0;
    auto alloc = [&](size_t bytes) -> void* {
        void* p = ws + off;
        off += (bytes + 255) & ~(size_t)255;
        return p;
    };
    f16* WtQ = (f16*)alloc((size_t)5120 * 256 * 2);   // W1|W3|W4|W5 transposed [5120][256]
    f16* Wt2 = (f16*)alloc((size_t)1024 * 2048 * 2);
    f16* E   = (f16*)alloc((size_t)RP * 256 * 2);
    f16* Rb  = (f16*)alloc((size_t)RP * 2048 * 2);
    f16* Mt  = (f16*)alloc((size_t)RP * 1024 * 2);
    f16* Pt  = (f16*)alloc((size_t)RP * 1024 * 2);
    f16* Ut  = (f16*)alloc((size_t)RP * 1024 * 2);
    float* partial = (float*)alloc((size_t)2048 * 4);
    (void)ws_size; (void)in_sizes; (void)n_in; (void)out_size;

    // weights -> f16 transposed [N][K] (LDS-tiled, coalesced both ways)
    tposeq_kernel<<<dim3(4, 80), 256, 0, stream>>>(W1, W3, W4, W5, WtQ);
    tpose_kernel<<<dim3(32, 16), 256, 0, stream>>>(W2, Wt2, 2048, 1024);
    ecast_kernel<<<RP / 4, 256, 0, stream>>>(emb, E);

    // fused per-vocab tables: E @ [W1 | W3/W4 interleaved | W5]  (N=5120, K=256)
    // 160x256 tile, BK=32: grid 64x20 = 1280, 2 blocks/CU co-resident
    gemm_main<0><<<(RP / 160) * (5120 / 256), 512, 0, stream>>>(
        E, WtQ, 5120, 256, 5120 / 256, b1, b3, b4, Rb, Pt, Ut);
    // Mt = tanh(relu(...) @ W2 + b2)  (N=1024, K=2048)
    // 160x128 tile, BK=64: grid 64x8 = 512, 2 blocks/CU co-resident
    gemm_main<1><<<(RP / 160) * (1024 / 128), 512, 0, stream>>>(
        Rb, Wt2, 1024, 2048, 1024 / 128, b2, nullptr, nullptr, Mt, nullptr, nullptr);

    // scan (XCD-sliced, 20-deep pipelined) + final projection reduce
    scan_slice_kernel<<<2048, 64, 0, stream>>>(tokens, Mt, Pt, Ut, state0, Wout, partial);
    final_kernel<<<1, 256, 0, stream>>>(partial, bout, out);
}

// Round 22
// 142.794 us; speedup vs baseline: 3.2216x; 1.0479x over previous
//
#include <hip/hip_runtime.h>
#include <math.h>

typedef _Float16 f16;
typedef _Float16 f16x2 __attribute__((ext_vector_type(2)));
typedef _Float16 f16x4 __attribute__((ext_vector_type(4)));
typedef _Float16 f16x8 __attribute__((ext_vector_type(8)));
typedef float f32x4 __attribute__((ext_vector_type(4)));

#define AS1 __attribute__((address_space(1)))
#define AS3 __attribute__((address_space(3)))

__device__ __forceinline__ void gload_lds16(const void* g, void* l) {
    __builtin_amdgcn_global_load_lds((AS1 void*)(g), (AS3 void*)(l), 16, 0, 0);
}

// fast transcendentals: v_exp_f32 (exp2) + v_rcp_f32, ~1 ulp, correct saturation
__device__ __forceinline__ float sigmoid_fast(float v) {
    return __builtin_amdgcn_rcpf(1.f + __builtin_amdgcn_exp2f(-1.44269504f * v));
}
__device__ __forceinline__ float tanh_fast(float v) {
    return 1.f - 2.f * __builtin_amdgcn_rcpf(1.f + __builtin_amdgcn_exp2f(2.88539008f * v));
}

// ---------------- fused prep: all weight transposes + embedding cast in ONE launch --------------
// blocks 0..319    : W1|W3|W4|W5 -> WtQ[5120][256] (LDS-tiled 64x64 transpose+cast)
// blocks 320..831  : W2 -> Wt2[1024][2048]
// blocks 832..3391 : emb -> E f16 (padded rows zeroed)
__global__ __launch_bounds__(256) void prep_kernel(
    const float* __restrict__ W1, const float* __restrict__ W2, const float* __restrict__ W3,
    const float* __restrict__ W4, const float* __restrict__ W5, const float* __restrict__ emb,
    f16* __restrict__ WtQ, f16* __restrict__ Wt2, f16* __restrict__ E) {
    const int bid = blockIdx.x;
    const int tid = threadIdx.x;

    if (bid >= 832) {                     // ---- ecast ----
        int r = (bid - 832) * 4 + (tid >> 6);
        int c = (tid & 63) * 4;
        float4 v = make_float4(0.f, 0.f, 0.f, 0.f);
        if (r < 10000) v = *(const float4*)&emb[(size_t)r * 256 + c];
        f16x4 h;
        h[0] = (f16)v.x; h[1] = (f16)v.y; h[2] = (f16)v.z; h[3] = (f16)v.w;
        *(f16x4*)&E[(size_t)r * 256 + c] = h;
        return;
    }

    __shared__ float T[64][65];
    const int rr = tid >> 4, cc = (tid & 15) * 4;

    const float* W; int nw, n0, k0; f16* Wo; int orow, Kd;
    if (bid < 320) {                      // ---- tposeq: W1|W3|W4|W5 -> WtQ ----
        int y = bid >> 2;                 // [0,80)
        k0 = (bid & 3) * 64;
        if (y < 32)      { W = W1; nw = 2048; n0 = y * 64;        orow = 0;    }
        else if (y < 48) { W = W3; nw = 1024; n0 = (y - 32) * 64; orow = 2048; }
        else if (y < 64) { W = W4; nw = 1024; n0 = (y - 48) * 64; orow = 3072; }
        else             { W = W5; nw = 1024; n0 = (y - 64) * 64; orow = 4096; }
        Wo = WtQ; Kd = 256;
    } else {                              // ---- tpose W2 [2048][1024] -> Wt2 ----
        int idx = bid - 320;              // [0,512): 32 k-tiles x 16 n-tiles
        k0 = (idx & 31) * 64;
        n0 = (idx >> 5) * 64;
        W = W2; nw = 1024; orow = 0; Wo = Wt2; Kd = 2048;
    }
#pragma unroll
    for (int p = 0; p < 4; ++p) {
        int k = rr + p * 16;
        float4 v = *(const float4*)&W[(size_t)(k0 + k) * nw + n0 + cc];
        T[k][cc] = v.x; T[k][cc + 1] = v.y; T[k][cc + 2] = v.z; T[k][cc + 3] = v.w;
    }
    __syncthreads();
#pragma unroll
    for (int p = 0; p < 4; ++p) {
        int n = rr + p * 16;
        f16x4 h;
        h[0] = (f16)T[cc][n]; h[1] = (f16)T[cc + 1][n];
        h[2] = (f16)T[cc + 2][n]; h[3] = (f16)T[cc + 3][n];
        *(f16x4*)&Wo[(size_t)(orow + n0 + n) * Kd + k0 + cc] = h;
    }
}

// ---------------- GEMM: C = act(A @ Bt^T + bias), 160-row tiles, double-buffered ----------------
// r21-proven config (149.6 us): LDS < 80 KB -> 2 blocks/CU (16 waves/CU). VGPR cap at
// launch_bounds(512,4) = 128 — fits acc+frags ((512,6)'s cap of 85 caused spill catastrophe, r20).
//   MODE 0: 160x256, BK=32 (dbuf 2x26 KB; alloc = Cs 80 KB = exactly 2/CU). Row-phase swizzle
//           (row>>1)&3 (r11-verified, 0 conflicts). grid 64x20 = 1280.
//   MODE 1: 160x128, BK=64 (dbuf 72 KB -> 2/CU). grid 64x8 = 512.
// 8 waves (2M x 4N); per-wave 80x(BN/4): acc[5][4] / acc[5][2].
// MODE 0 (N=5120): col<2048 relu+b1->O0[.,2048]; cols 2048..4095 W3/W4 interleaved (16-col
//   groups): even frag = sigmoid(.+b3), odd = tanh(.+b4) -> p=i*g -> O1 (Pt). col>=4096 relu->O3.
// MODE 1: tanh+bias -> O0 stride 1024
template <int MODE>
__global__ __launch_bounds__(512, 4) void gemm_main(
    const f16* __restrict__ A, const f16* __restrict__ Bt, int N, int K, int CT,
    const float* __restrict__ bb1, const float* __restrict__ bb3, const float* __restrict__ bb4,
    f16* __restrict__ O0, f16* __restrict__ O1, f16* __restrict__ O3) {
    constexpr int BN    = (MODE == 0) ? 256 : 128;
    constexpr int BK    = (MODE == 0) ? 32 : 64;
    constexpr int NF    = BN / 64;                 // per-wave 16-col fragments
    constexpr int WNOFF = BN / 4;                  // per-wave N span
    constexpr int SLOTS = BK / 8, SMASK = SLOTS - 1;
    constexpr int LOG2S = (BK == 32) ? 2 : 3;
    constexpr int RSH   = (BK == 32) ? 1 : 0;      // row-phase shift for swizzle
    constexpr int ABUF  = 160 * BK;                // f16 per A buffer
    constexpr int BBUF  = BN * BK;
    constexpr int BUFSZ = ABUF + BBUF;
    constexpr int ACH   = 160 * SLOTS;             // A 16B chunks
    constexpr int BCH   = BN * SLOTS;              // B 16B chunks (1024 both modes)
    constexpr int AIT   = (ACH + 511) / 512;
    constexpr int BIT   = BCH / 512;
    constexpr int SMSZ  = (MODE == 0) ? 40960 : 36864;   // f16: 80 KB / 72 KB
    __shared__ __align__(16) f16 SM[SMSZ];
    f16* Cs = SM;
    // bijective XCD remap (m204), then row-major decode: consecutive wg share A-panel
    const int nwg = gridDim.x, orig = blockIdx.x;
    const int q = nwg >> 3, rm = nwg & 7;
    const int xcd = orig & 7, loc = orig >> 3;
    const int wg = (xcd < rm ? xcd * (q + 1) : rm * (q + 1) + (xcd - rm) * q) + loc;
    const int rowT = wg / CT, colT = wg - rowT * CT;
    const int row0 = rowT * 160, col0 = colT * BN;

    const int tid = threadIdx.x;
    const int wave = tid >> 6, lane = tid & 63;
    const int wr = wave >> 2, wc = wave & 3;       // 2 x 4 wave grid
    const int lo16 = lane & 15, hi4 = lane >> 4;

    const bool PM = (MODE == 0) && (col0 >= 2048) && (col0 < 4096);  // block-uniform

    f32x4 acc[5][NF] = {};

    // ---- hoisted staging sources (k0-invariant) ----
    const f16* aptr[AIT]; int adst[AIT];
    const f16* bptr[BIT]; int bdst[BIT];
#pragma unroll
    for (int it = 0; it < AIT; ++it) {
        int c = it * 512 + tid;
        int r = c >> LOG2S, sl = c & SMASK;
        int kc = (sl ^ ((r >> RSH) & SMASK)) << 3;  // pre-swizzled global source (rule #21)
        aptr[it] = A + (size_t)(row0 + (r < 160 ? r : 0)) * K + kc;
        adst[it] = c * 8;
    }
#pragma unroll
    for (int it = 0; it < BIT; ++it) {
        int c = it * 512 + tid;
        int r = c >> LOG2S, sl = c & SMASK;
        int kc = (sl ^ ((r >> RSH) & SMASK)) << 3;
        int brow = col0 + r;
        if (PM) {                                   // W3/W4 16-col interleave remap (hoisted)
            int qc = col0 - 2048 + r;
            int grp = qc >> 5, q2 = qc & 31;
            brow = (q2 < 16) ? (2048 + grp * 16 + q2) : (3072 + grp * 16 + (q2 - 16));
        }
        bptr[it] = Bt + (size_t)brow * K + kc;
        bdst[it] = c * 8;
    }

    auto stage = [&](int buf, int k0) {
        f16* As = SM + buf * BUFSZ;
        f16* Bs = As + ABUF;
#pragma unroll
        for (int it = 0; it < AIT; ++it)
            if ((it + 1) * 512 <= ACH || tid < ACH - it * 512)
                gload_lds16(aptr[it] + k0, &As[adst[it]]);
#pragma unroll
        for (int it = 0; it < BIT; ++it)
            gload_lds16(bptr[it] + k0, &Bs[bdst[it]]);
    };

    const int nt = K / BK;
    stage(0, 0);
    __syncthreads();                               // buf0 ready
    for (int t = 0; t < nt; ++t) {
        if (t + 1 < nt) stage((t + 1) & 1, (t + 1) * BK);   // prefetch in flight during MFMA
        const f16* As = SM + (t & 1) * BUFSZ;
        const f16* Bs = As + ABUF;
#pragma unroll
        for (int kk = 0; kk < BK; kk += 32) {
            const int s0 = (kk >> 3) + hi4;
            f16x8 af[5], bf[NF];
#pragma unroll
            for (int m = 0; m < 5; ++m) {
                int row = wr * 80 + m * 16 + lo16;
                af[m] = *(const f16x8*)&As[row * BK + ((s0 ^ ((row >> RSH) & SMASK)) << 3)];
            }
#pragma unroll
            for (int n = 0; n < NF; ++n) {
                int row = wc * WNOFF + n * 16 + lo16;
                bf[n] = *(const f16x8*)&Bs[row * BK + ((s0 ^ ((row >> RSH) & SMASK)) << 3)];
            }
#pragma unroll
            for (int m = 0; m < 5; ++m)
#pragma unroll
                for (int n = 0; n < NF; ++n)
                    acc[m][n] = __builtin_amdgcn_mfma_f32_16x16x32_f16(af[m], bf[n], acc[m][n], 0, 0, 0);
        }
        __syncthreads();   // drains prefetch (covered by MFMA + co-resident block) + seals reads
    }

    if (MODE == 1) {
        // tanh+bias epilogue -> 160x128 tile of O0 (stride 1024)
        const float* bp = bb1 + col0;
#pragma unroll
        for (int n = 0; n < 2; ++n) {
            int col = wc * 32 + n * 16 + lo16;     // [0,128)
            float b = bp[col];
            int ch = col >> 3, el = col & 7;
#pragma unroll
            for (int m = 0; m < 5; ++m)
#pragma unroll
                for (int j = 0; j < 4; ++j) {
                    int row = wr * 80 + m * 16 + hi4 * 4 + j;
                    Cs[row * 128 + ((ch ^ (row & 15)) << 3) + el] = (f16)tanh_fast(acc[m][n][j] + b);
                }
        }
        __syncthreads();
#pragma unroll
        for (int it = 0; it < 5; ++it) {           // 160x16 chunks = 2560 = 5x512
            int idx = it * 512 + tid;
            int row = idx >> 4, ch = idx & 15;
            f16x8 v = *(const f16x8*)&Cs[row * 128 + ((ch ^ (row & 15)) << 3)];
            *(f16x8*)&O0[(size_t)(row0 + row) * 1024 + col0 + ch * 8] = v;
        }
        return;
    }

    if (PM) {
        // p-fusion epilogue: p = sigmoid(acc_even + b3) * tanh(acc_odd + b4) -> 160x128 Pt tile
        const int pcol0 = (col0 - 2048) >> 1;
#pragma unroll
        for (int p = 0; p < 2; ++p) {
            int colP = wc * 32 + p * 16 + lo16;    // [0,128) local Pt col
            float bi = bb3[pcol0 + colP], bg = bb4[pcol0 + colP];
            int ch = colP >> 3, el = colP & 7;
#pragma unroll
            for (int m = 0; m < 5; ++m)
#pragma unroll
                for (int j = 0; j < 4; ++j) {
                    int row = wr * 80 + m * 16 + hi4 * 4 + j;
                    float pi = sigmoid_fast(acc[m][2 * p][j] + bi);
                    float pg = tanh_fast(acc[m][2 * p + 1][j] + bg);
                    Cs[row * 128 + ((ch ^ (row & 15)) << 3) + el] = (f16)(pi * pg);
                }
        }
        __syncthreads();
#pragma unroll
        for (int it = 0; it < 5; ++it) {           // 160x16 chunks = 2560 = 5x512
            int idx = it * 512 + tid;
            int row = idx >> 4, ch = idx & 15;
            f16x8 v = *(const f16x8*)&Cs[row * 128 + ((ch ^ (row & 15)) << 3)];
            *(f16x8*)&O1[(size_t)(row0 + row) * 1024 + pcol0 + ch * 8] = v;
        }
        return;
    }

    // MODE 0 non-interleaved tiles: relu (+b1 for col<2048)
    f16* Oe; size_t ostr; const float* bp;
    if (col0 < 2048) { Oe = O0 + col0;          ostr = 2048; bp = bb1 + col0; }
    else             { Oe = O3 + (col0 - 4096); ostr = 1024; bp = nullptr;    }

#pragma unroll
    for (int n = 0; n < NF; ++n) {
        int col = wc * WNOFF + n * 16 + lo16;      // [0,256)
        float b = bp ? bp[col] : 0.f;
        int ch = col >> 3, el = col & 7;
#pragma unroll
        for (int m = 0; m < 5; ++m)
#pragma unroll
            for (int j = 0; j < 4; ++j) {
                int row = wr * 80 + m * 16 + hi4 * 4 + j;
                Cs[row * 256 + ((ch ^ (row & 31)) << 3) + el] = (f16)fmaxf(acc[m][n][j] + b, 0.f);
            }
    }
    __syncthreads();

    // coalesced store: 160x32 chunks = 5120 = 10x512; 32 lanes cover one 512B row
#pragma unroll
    for (int it = 0; it < 10; ++it) {
        int idx = it * 512 + tid;
        int row = idx >> 5, ch = idx & 31;
        f16x8 v = *(const f16x8*)&Cs[row * 256 + ((ch ^ (row & 31)) << 3)];
        *(f16x8*)&Oe[(size_t)(row0 + row) * ostr + ch * 8] = v;
    }
}

// ---------------- scan over T, XCD-sliced: block = (batch b, unit-slice x of 128) ----------------
// blockIdx = b*8 + x -> round-robin dispatch pins slice x to XCD x (L2 affinity).
// 32-slot / 20-deep static software pipeline: 60 loads in flight (vmcnt cap 63 — 20 is max depth
// at 3 loads/step). All slot indices compile-time (rule #20).
__global__ __launch_bounds__(64) void scan_slice_kernel(
    const int* __restrict__ tokens, const f16* __restrict__ Mt, const f16* __restrict__ Pt,
    const f16* __restrict__ Ut, const float* __restrict__ state0,
    const float* __restrict__ Wout, float* __restrict__ partial) {
    __shared__ int toks[288];
    const int bid = blockIdx.x;
    const int b = bid >> 3, x = bid & 7;
    const int lane = threadIdx.x;
    for (int t = lane; t < 288; t += 64) toks[t] = (t < 250) ? tokens[b * 250 + t] : 0;
    __syncthreads();

    const int u0 = x * 128 + lane * 2;
    float2 sv = *(const float2*)&state0[(size_t)b * 1024 + u0];
    float s0 = sv.x, s1 = sv.y;

    f16x2 m[32], p[32], u[32];
#pragma unroll
    for (int k = 0; k < 20; ++k) {   // preload t=0..19 into slots 0..19
        size_t nb = (size_t)toks[k] * 1024 + u0;
        m[k] = *(const f16x2*)&Mt[nb];
        p[k] = *(const f16x2*)&Pt[nb];
        u[k] = *(const f16x2*)&Ut[nb];
    }

    // main: t = 0..223 (7 x 32 unrolled, slots static); loads target t+20
    for (int tb = 0; tb < 224; tb += 32) {
#pragma unroll
        for (int k = 0; k < 32; ++k) {
            const int ls = (k + 20) & 31;        // compile-time slot for t+20
            size_t nb = (size_t)toks[tb + k + 20] * 1024 + u0;
            m[ls] = *(const f16x2*)&Mt[nb];
            p[ls] = *(const f16x2*)&Pt[nb];
            u[ls] = *(const f16x2*)&Ut[nb];
            float y0 = fmaxf((float)m[k][0] * s0 + (float)p[k][0], 0.f);
            s0 = fmaxf((float)u[k][0] + y0, 0.f);
            float y1 = fmaxf((float)m[k][1] * s1 + (float)p[k][1], 0.f);
            s1 = fmaxf((float)u[k][1] + y1, 0.f);
        }
    }
    // tail: t = 224..249 use slots 0..25; slots 20..25 reloaded with t=244..249
#pragma unroll
    for (int k = 0; k < 26; ++k) {
        if (k < 6) {
            const int ls = k + 20;
            size_t nb = (size_t)toks[244 + k] * 1024 + u0;
            m[ls] = *(const f16x2*)&Mt[nb];
            p[ls] = *(const f16x2*)&Pt[nb];
            u[ls] = *(const f16x2*)&Ut[nb];
        }
        float y0 = fmaxf((float)m[k][0] * s0 + (float)p[k][0], 0.f);
        s0 = fmaxf((float)u[k][0] + y0, 0.f);
        float y1 = fmaxf((float)m[k][1] * s1 + (float)p[k][1], 0.f);
        s1 = fmaxf((float)u[k][1] + y1, 0.f);
    }

    float2 wv = *(const float2*)&Wout[u0];
    float part = s0 * wv.x + s1 * wv.y;
#pragma unroll
    for (int o = 32; o > 0; o >>= 1) part += __shfl_down(part, o, 64);
    if (lane == 0) partial[bid] = part;
}

// ---------------- final reduce: out[b] = sigmoid(sum_x partial[b*8+x] + bout) ----------------
__global__ __launch_bounds__(256) void final_kernel(const float* __restrict__ partial,
                                                    const float* __restrict__ bout,
                                                    float* __restrict__ out) {
    int b = threadIdx.x;
    float tot = bout[0];
#pragma unroll
    for (int w = 0; w < 8; ++w) tot += partial[b * 8 + w];
    out[b] = sigmoid_fast(tot);
}

extern "C" void kernel_launch(void* const* d_in, const int* in_sizes, int n_in,
                              void* d_out, int out_size, void* d_ws, size_t ws_size,
                              hipStream_t stream) {
    const int*   tokens = (const int*)  d_in[0];
    const float* emb    = (const float*)d_in[1];
    const float* W1     = (const float*)d_in[2];
    const float* b1     = (const float*)d_in[3];
    const float* W2     = (const float*)d_in[4];
    const float* b2     = (const float*)d_in[5];
    const float* W3     = (const float*)d_in[6];
    const float* b3     = (const float*)d_in[7];
    const float* W4     = (const float*)d_in[8];
    const float* b4     = (const float*)d_in[9];
    const float* W5     = (const float*)d_in[10];
    const float* Wout   = (const float*)d_in[11];
    const float* bout   = (const float*)d_in[12];
    const float* state0 = (const float*)d_in[13];
    float* out = (float*)d_out;

    const int RP = 10240;  // padded vocab rows: 64 x 160 (gemm M-tiles)

    char* ws = (char*)d_ws;
    size_t off = 0;
    auto alloc = [&](size_t bytes) -> void* {
        void* p = ws + off;
        off += (bytes + 255) & ~(size_t)255;
        return p;
    };
    f16* WtQ = (f16*)alloc((size_t)5120 * 256 * 2);   // W1|W3|W4|W5 transposed [5120][256]
    f16* Wt2 = (f16*)alloc((size_t)1024 * 2048 * 2);
    f16* E   = (f16*)alloc((size_t)RP * 256 * 2);
    f16* Rb  = (f16*)alloc((size_t)RP * 2048 * 2);
    f16* Mt  = (f16*)alloc((size_t)RP * 1024 * 2);
    f16* Pt  = (f16*)alloc((size_t)RP * 1024 * 2);
    f16* Ut  = (f16*)alloc((size_t)RP * 1024 * 2);
    float* partial = (float*)alloc((size_t)2048 * 4);
    (void)ws_size; (void)in_sizes; (void)n_in; (void)out_size;

    // fused prep: all transposes + embedding cast in one launch (320 + 512 + 2560 blocks)
    prep_kernel<<<832 + RP / 4, 256, 0, stream>>>(W1, W2, W3, W4, W5, emb, WtQ, Wt2, E);

    // fused per-vocab tables: E @ [W1 | W3/W4 interleaved | W5]  (N=5120, K=256)
    // 160x256 tile, BK=32: grid 64x20 = 1280, 2 blocks/CU co-resident
    gemm_main<0><<<(RP / 160) * (5120 / 256), 512, 0, stream>>>(
        E, WtQ, 5120, 256, 5120 / 256, b1, b3, b4, Rb, Pt, Ut);
    // Mt = tanh(relu(...) @ W2 + b2)  (N=1024, K=2048)
    // 160x128 tile, BK=64: grid 64x8 = 512, 2 blocks/CU co-resident
    gemm_main<1><<<(RP / 160) * (1024 / 128), 512, 0, stream>>>(
        Rb, Wt2, 1024, 2048, 1024 / 128, b2, nullptr, nullptr, Mt, nullptr, nullptr);

    // scan (XCD-sliced, 20-deep pipelined) + final projection reduce
    scan_slice_kernel<<<2048, 64, 0, stream>>>(tokens, Mt, Pt, Ut, state0, Wout, partial);
    final_kernel<<<1, 256, 0, stream>>>(partial, bout, out);
}